// Round 3
// baseline (842.667 us; speedup 1.0000x reference)
//
#include <hip/hip_runtime.h>

// ---------------------------------------------------------------------------
// SPDBatchNormMean forward, B=8192, n=64, fp32. Eigendecomp-free:
//   G0 = mean(x); Gs/Gis = G0^{±1/2} (Newton-Schulz); M = mean log(Gis x Gis)
//   (deg-12 Chebyshev on [0.3,4.0]); G1 = Gs expm(M) Gs; Gis1 = G1^{-1/2};
//   C = Bs Gis1 (Bs = bias^{1/2}); out = C x C^T.
// Round 3: k3/k5 on 256-thread blocks (3 blocks/CU via 5-6 LDS arrays),
//   packed bf16 cvt, X/P0 hi-only in k3 (incoherent noise averages out),
//   DEG 12. Gis/C kept hi/lo (coherent error) and read from LDS per use.
// ---------------------------------------------------------------------------

#define BATCH 8192
#define NMAT 64
#define MSIZE 4096
#define NBLK_RED 128
#define NBLK_MM 768
#define DEG 12
#define CHEB_LO 0.30f
#define CHEB_HI 4.00f
#define NS_ITERS_MEAN 10
#define NS_ITERS_BIAS 12
#define GSTR 520 /* padded k-group stride (65*8 elems, 16B-aligned) */

// workspace layout (floats): PM partials (768 slots, 12.6 MB) overlay PG
// partials (128 slots, consumed before k3 writes).
#define PM_OFF 0
#define PG_OFF 0
#define G_OFF (PM_OFF + NBLK_MM * MSIZE)
#define BS_OFF (G_OFF + MSIZE)
#define GS_OFF (BS_OFF + MSIZE)
#define GIS_OFF (GS_OFF + MSIZE)
#define MBAR_OFF (GIS_OFF + MSIZE)
#define C_OFF (MBAR_OFF + MSIZE)

typedef __attribute__((ext_vector_type(8))) short bf16x8;
typedef __attribute__((ext_vector_type(16))) float floatx16;
#define MFMA(a, b, c) __builtin_amdgcn_mfma_f32_32x32x16_bf16(a, b, c, 0, 0, 0)

__device__ __forceinline__ unsigned f2bf_bits(float x) {
  unsigned u = __float_as_uint(x);
  return (u + 0x7fffu + ((u >> 16) & 1u)) >> 16;
}
__device__ __forceinline__ float bfbits2f(unsigned bits) {
  return __uint_as_float(bits << 16);
}

// packed f32x2 -> bf16x2 (low = a, high = b), RTNE
__device__ __forceinline__ unsigned cvt2(float a, float b) {
#if __has_builtin(__builtin_amdgcn_cvt_pk_bf16_f32)
  auto r = __builtin_amdgcn_cvt_pk_bf16_f32(a, b);
  union {
    decltype(r) v;
    unsigned u;
  } cv;
  cv.v = r;
  return cv.u;
#else
  return f2bf_bits(a) | (f2bf_bits(b) << 16);
#endif
}

// Stage a row-major 64x64 fp32 global matrix M into hi/lo bf16 LDS arrays in
// B-layout holding M^T: arr(k,n) = M[n][k]. 256 threads (st).
__device__ __forceinline__ void stageT(const float* __restrict__ src, short* ah,
                                       short* al, int st) {
#pragma unroll
  for (int jb = 0; jb < 4; ++jb) {
    int flat = jb * 1024 + st * 4;
    float4 v = *reinterpret_cast<const float4*>(src + flat);
    int i = flat >> 6;
    int j0 = flat & 63;
    int addr = (j0 >> 3) * GSTR + i * 8 + (j0 & 7);
    unsigned h01 = cvt2(v.x, v.y), h23 = cvt2(v.z, v.w);
    float r0 = v.x - bfbits2f(h01 & 0xffffu);
    float r1 = v.y - bfbits2f(h01 >> 16);
    float r2 = v.z - bfbits2f(h23 & 0xffffu);
    float r3 = v.w - bfbits2f(h23 >> 16);
    unsigned l01 = cvt2(r0, r1), l23 = cvt2(r2, r3);
    uint2 hp, lp;
    hp.x = h01;
    hp.y = h23;
    lp.x = l01;
    lp.y = l23;
    *reinterpret_cast<uint2*>(ah + addr) = hp;
    *reinterpret_cast<uint2*>(al + addr) = lp;
  }
}

// hi-only variant
__device__ __forceinline__ void stageThi(const float* __restrict__ src,
                                         short* ah, int st) {
#pragma unroll
  for (int jb = 0; jb < 4; ++jb) {
    int flat = jb * 1024 + st * 4;
    float4 v = *reinterpret_cast<const float4*>(src + flat);
    int i = flat >> 6;
    int j0 = flat & 63;
    int addr = (j0 >> 3) * GSTR + i * 8 + (j0 & 7);
    uint2 hp;
    hp.x = cvt2(v.x, v.y);
    hp.y = cvt2(v.z, v.w);
    *reinterpret_cast<uint2*>(ah + addr) = hp;
  }
}

// Fragment read: elements j=0..7 at k = kb*16 + q*8 + j, column n.
__device__ __forceinline__ bf16x8 readFrag(const short* a, int kb, int q,
                                           int n) {
  return *reinterpret_cast<const bf16x8*>(a + (kb * 2 + q) * GSTR + n * 8);
}

// Store 16 C/D-layout fp32 regs into B-layout array as bf16 (arr(k,n)=v).
__device__ __forceinline__ void storeChi(short* dh, const float* v, int R,
                                         int col, int q) {
#pragma unroll
  for (int g4 = 0; g4 < 4; ++g4) {
    int addr = (4 * R + g4) * GSTR + col * 8 + 4 * q;
    uint2 hp;
    hp.x = cvt2(v[4 * g4 + 0], v[4 * g4 + 1]);
    hp.y = cvt2(v[4 * g4 + 2], v[4 * g4 + 3]);
    *reinterpret_cast<uint2*>(dh + addr) = hp;
  }
}
__device__ __forceinline__ void storeChl(short* dh, short* dl, const float* v,
                                         int R, int col, int q) {
#pragma unroll
  for (int g4 = 0; g4 < 4; ++g4) {
    int addr = (4 * R + g4) * GSTR + col * 8 + 4 * q;
    float a0 = v[4 * g4 + 0], a1 = v[4 * g4 + 1];
    float a2 = v[4 * g4 + 2], a3 = v[4 * g4 + 3];
    unsigned h01 = cvt2(a0, a1), h23 = cvt2(a2, a3);
    float r0 = a0 - bfbits2f(h01 & 0xffffu);
    float r1 = a1 - bfbits2f(h01 >> 16);
    float r2 = a2 - bfbits2f(h23 & 0xffffu);
    float r3 = a3 - bfbits2f(h23 >> 16);
    unsigned l01 = cvt2(r0, r1), l23 = cvt2(r2, r3);
    uint2 hp, lp;
    hp.x = h01;
    hp.y = h23;
    lp.x = l01;
    lp.y = l23;
    *reinterpret_cast<uint2*>(dh + addr) = hp;
    *reinterpret_cast<uint2*>(dl + addr) = lp;
  }
}

// ============================ vector-ALU helpers (k1/k2/k4) ================

__device__ __forceinline__ void mm64T(const float* __restrict__ A,
                                      const float* __restrict__ B, int rt,
                                      int ct, float p[4][4]) {
#pragma unroll
  for (int i = 0; i < 4; ++i)
#pragma unroll
    for (int j = 0; j < 4; ++j) p[i][j] = 0.0f;
#pragma unroll 4
  for (int k = 0; k < NMAT; ++k) {
    float4 a = *reinterpret_cast<const float4*>(A + k * NMAT + rt * 4);
    float4 b = *reinterpret_cast<const float4*>(B + k * NMAT + ct * 4);
    p[0][0] = fmaf(a.x, b.x, p[0][0]);
    p[0][1] = fmaf(a.x, b.y, p[0][1]);
    p[0][2] = fmaf(a.x, b.z, p[0][2]);
    p[0][3] = fmaf(a.x, b.w, p[0][3]);
    p[1][0] = fmaf(a.y, b.x, p[1][0]);
    p[1][1] = fmaf(a.y, b.y, p[1][1]);
    p[1][2] = fmaf(a.y, b.z, p[1][2]);
    p[1][3] = fmaf(a.y, b.w, p[1][3]);
    p[2][0] = fmaf(a.z, b.x, p[2][0]);
    p[2][1] = fmaf(a.z, b.y, p[2][1]);
    p[2][2] = fmaf(a.z, b.z, p[2][2]);
    p[2][3] = fmaf(a.z, b.w, p[2][3]);
    p[3][0] = fmaf(a.w, b.x, p[3][0]);
    p[3][1] = fmaf(a.w, b.y, p[3][1]);
    p[3][2] = fmaf(a.w, b.z, p[3][2]);
    p[3][3] = fmaf(a.w, b.w, p[3][3]);
  }
}

__device__ __forceinline__ void storeTile(float* dst, int rt, int ct,
                                          const float p[4][4]) {
#pragma unroll
  for (int i = 0; i < 4; ++i)
    *reinterpret_cast<float4*>(dst + (rt * 4 + i) * NMAT + ct * 4) =
        make_float4(p[i][0], p[i][1], p[i][2], p[i][3]);
}

__device__ __forceinline__ void loadMat(float* dst,
                                        const float* __restrict__ src,
                                        int tid) {
#pragma unroll
  for (int j = 0; j < 4; ++j)
    *reinterpret_cast<float4*>(dst + j * 1024 + tid * 4) =
        *reinterpret_cast<const float4*>(src + j * 1024 + tid * 4);
}

__device__ __forceinline__ float4 id4(int base) {
  return make_float4(((base + 0) % 65) == 0 ? 1.f : 0.f,
                     ((base + 1) % 65) == 0 ? 1.f : 0.f,
                     ((base + 2) % 65) == 0 ? 1.f : 0.f,
                     ((base + 3) % 65) == 0 ? 1.f : 0.f);
}

__device__ float block_ns(const float* lA, float* lY, float* lZ, float* lW,
                          float* red, int iters) {
  const int tid = threadIdx.x;
  const int rt = tid >> 4, ct = tid & 15;
  float ss = 0.0f;
#pragma unroll
  for (int j = 0; j < 4; ++j) {
    float4 v = *reinterpret_cast<const float4*>(lA + j * 1024 + tid * 4);
    ss += v.x * v.x + v.y * v.y + v.z * v.z + v.w * v.w;
  }
  red[tid] = ss;
  __syncthreads();
  for (int off = 128; off > 0; off >>= 1) {
    if (tid < off) red[tid] += red[tid + off];
    __syncthreads();
  }
  const float c = sqrtf(red[0] * 0.5f);
  const float rc = 1.0f / c;
#pragma unroll
  for (int j = 0; j < 4; ++j) {
    int base = j * 1024 + tid * 4;
    float4 v = *reinterpret_cast<const float4*>(lA + base);
    v.x *= rc;
    v.y *= rc;
    v.z *= rc;
    v.w *= rc;
    *reinterpret_cast<float4*>(lY + base) = v;
    *reinterpret_cast<float4*>(lZ + base) = id4(base);
  }
  __syncthreads();
  for (int it = 0; it < iters; ++it) {
    float p[4][4];
    mm64T(lZ, lY, rt, ct, p);
    float w[4][4];
#pragma unroll
    for (int i = 0; i < 4; ++i)
#pragma unroll
      for (int j = 0; j < 4; ++j)
        w[i][j] = ((rt * 4 + i) == (ct * 4 + j) ? 1.5f : 0.0f) - 0.5f * p[i][j];
    storeTile(lW, rt, ct, w);
    __syncthreads();
    float py[4][4], pz[4][4];
    mm64T(lY, lW, rt, ct, py);
    mm64T(lW, lZ, rt, ct, pz);
    __syncthreads();
    storeTile(lY, rt, ct, py);
    storeTile(lZ, rt, ct, pz);
    __syncthreads();
  }
  return c;
}

// K1: blocks [0,NBLK_RED) partial-sum x; block NBLK_RED does Bs = bias^{1/2}.
__global__ __launch_bounds__(256) void k1_mean_bias(
    const float* __restrict__ x, const float* __restrict__ bias,
    float* __restrict__ ws) {
  const int tid = threadIdx.x;
  if (blockIdx.x < NBLK_RED) {
    float acc[16];
#pragma unroll
    for (int j = 0; j < 16; ++j) acc[j] = 0.f;
    for (int i = blockIdx.x; i < BATCH; i += NBLK_RED) {
      const float* src = x + (size_t)i * MSIZE;
#pragma unroll
      for (int j = 0; j < 4; ++j) {
        float4 v = *reinterpret_cast<const float4*>(src + j * 1024 + tid * 4);
        acc[j * 4 + 0] += v.x;
        acc[j * 4 + 1] += v.y;
        acc[j * 4 + 2] += v.z;
        acc[j * 4 + 3] += v.w;
      }
    }
    float* dst = ws + PG_OFF + (size_t)blockIdx.x * MSIZE;
#pragma unroll
    for (int j = 0; j < 4; ++j)
      *reinterpret_cast<float4*>(dst + j * 1024 + tid * 4) = make_float4(
          acc[j * 4 + 0], acc[j * 4 + 1], acc[j * 4 + 2], acc[j * 4 + 3]);
  } else {
    __shared__ __align__(16) float lA[MSIZE], lY[MSIZE], lZ[MSIZE], lW[MSIZE];
    __shared__ float red[257];
    loadMat(lA, bias, tid);
    __syncthreads();
    float c = block_ns(lA, lY, lZ, lW, red, NS_ITERS_BIAS);
    float sc = sqrtf(c);
#pragma unroll
    for (int j = 0; j < 4; ++j) {
      int base = j * 1024 + tid * 4;
      float4 v = *reinterpret_cast<const float4*>(lY + base);
      v.x *= sc;
      v.y *= sc;
      v.z *= sc;
      v.w *= sc;
      *reinterpret_cast<float4*>(ws + BS_OFF + base) = v;
    }
  }
}

__global__ __launch_bounds__(256) void k_reduce_parts(
    const float* __restrict__ src, float* __restrict__ dst, int nparts,
    float scale) {
  int e4 = blockIdx.x * 256 + threadIdx.x;
  float4 acc = make_float4(0.f, 0.f, 0.f, 0.f);
  for (int b = 0; b < nparts; ++b) {
    float4 v =
        *reinterpret_cast<const float4*>(src + (size_t)b * MSIZE + e4 * 4);
    acc.x += v.x;
    acc.y += v.y;
    acc.z += v.z;
    acc.w += v.w;
  }
  acc.x *= scale;
  acc.y *= scale;
  acc.z *= scale;
  acc.w *= scale;
  *reinterpret_cast<float4*>(dst + e4 * 4) = acc;
}

__global__ __launch_bounds__(256) void k2_mean_ns(float* __restrict__ ws) {
  __shared__ __align__(16) float lA[MSIZE], lY[MSIZE], lZ[MSIZE], lW[MSIZE];
  __shared__ float red[257];
  const int tid = threadIdx.x;
  loadMat(lA, ws + G_OFF, tid);
  __syncthreads();
  float c = block_ns(lA, lY, lZ, lW, red, NS_ITERS_MEAN);
  float sc = sqrtf(c), rs = 1.0f / sqrtf(c);
#pragma unroll
  for (int j = 0; j < 4; ++j) {
    int base = j * 1024 + tid * 4;
    float4 y = *reinterpret_cast<const float4*>(lY + base);
    float4 z = *reinterpret_cast<const float4*>(lZ + base);
    *reinterpret_cast<float4*>(ws + GS_OFF + base) =
        make_float4(y.x * sc, y.y * sc, y.z * sc, y.w * sc);
    *reinterpret_cast<float4*>(ws + GIS_OFF + base) =
        make_float4(z.x * rs, z.y * rs, z.z * rs, z.w * rs);
  }
}

// ============================ K3: MFMA Chebyshev log-sum ====================
// 256 threads = 4 waves, one matrix at a time; wave w4 owns C-tile
// (R=w4>>1, Cb=w4&1). 5 LDS arrays -> 3 blocks/CU. Grid-stride over mats.
__global__ __launch_bounds__(256, 3) void k3_logsum_mfma(
    const float* __restrict__ x, float* __restrict__ ws) {
  __shared__ __align__(16) short Gh[GSTR * 8], Gl[GSTR * 8];
  __shared__ __align__(16) short A0[GSTR * 8], B0[GSTR * 8], B1[GSTR * 8];
  const int tid = threadIdx.x;
  const int w4 = tid >> 6;
  const int R = w4 >> 1, Cb = w4 & 1;
  const int lane = tid & 63;
  const int ln = lane & 31, q = lane >> 5;
  const int col = 32 * Cb + ln;
  const int arow = 32 * R + ln;

  const float m = 0.5f * (CHEB_LO + CHEB_HI), hh = 0.5f * (CHEB_HI - CHEB_LO);
  const float invh = 1.0f / hh;
  const float beta = hh / m;
  const float zeta = (1.0f - sqrtf(1.0f - beta * beta)) / beta;
  const float a0c = logf(m) - log1pf(zeta * zeta);
  const float a1c = 2.0f * zeta;

  int rowv[16];
  float dg[16];
#pragma unroll
  for (int r = 0; r < 16; ++r) {
    rowv[r] = 32 * R + (r & 3) + 8 * (r >> 2) + 4 * q;
    dg[r] = (rowv[r] == col) ? 1.0f : 0.0f;
  }

  stageT(ws + GIS_OFF, Gh, Gl, tid);  // Gis hi/lo, persistent (coherent error)
  float Mac[16];
#pragma unroll
  for (int r = 0; r < 16; ++r) Mac[r] = 0.0f;
  __syncthreads();

  for (int mat = blockIdx.x; mat < BATCH; mat += NBLK_MM) {
    stageThi(x + (size_t)mat * MSIZE, A0, tid);  // X hi-only
    __syncthreads();
    // mm1: P0 = X * Gis (A = X-hi frags, B = Gis hi/lo from LDS)
    floatx16 acc;
#pragma unroll
    for (int r = 0; r < 16; ++r) acc[r] = 0.0f;
#pragma unroll
    for (int kb = 0; kb < 4; ++kb) {
      bf16x8 axh = readFrag(A0, kb, q, arow);
      bf16x8 gbh = readFrag(Gh, kb, q, col);
      bf16x8 gbl = readFrag(Gl, kb, q, col);
      acc = MFMA(axh, gbl, acc);
      acc = MFMA(axh, gbh, acc);
    }
    float t[16];
#pragma unroll
    for (int r = 0; r < 16; ++r) t[r] = acc[r];
    storeChi(B0, t, R, col, q);  // P0 hi-only
    __syncthreads();
    // mm2: S = Gis * P0 -> U = (S - mI)/h
#pragma unroll
    for (int r = 0; r < 16; ++r) acc[r] = 0.0f;
#pragma unroll
    for (int kb = 0; kb < 4; ++kb) {
      bf16x8 gah = readFrag(Gh, kb, q, arow);
      bf16x8 gal = readFrag(Gl, kb, q, arow);
      bf16x8 bph = readFrag(B0, kb, q, col);
      acc = MFMA(gal, bph, acc);
      acc = MFMA(gah, bph, acc);
    }
    float u[16], tm1[16], tm2[16];
#pragma unroll
    for (int r = 0; r < 16; ++r) {
      u[r] = (acc[r] - m * dg[r]) * invh;
      Mac[r] += a0c * dg[r] + a1c * u[r];
      tm1[r] = u[r];
      tm2[r] = dg[r];
    }
    storeChl(A0, B1, u, R, col, q);  // U hi -> A0 (X dead), U lo -> B1
    __syncthreads();
    bf16x8 uh[4], ul[4];
#pragma unroll
    for (int kb = 0; kb < 4; ++kb) {  // A-op U frags (symmetry), hi/lo
      uh[kb] = readFrag(A0, kb, q, arow);
      ul[kb] = readFrag(B1, kb, q, arow);
    }
    // k=2: T2 = 2 U*U - I (B-op = U-hi from A0)
#pragma unroll
    for (int r = 0; r < 16; ++r) acc[r] = 0.0f;
#pragma unroll
    for (int kb = 0; kb < 4; ++kb) {
      bf16x8 buh = readFrag(A0, kb, q, col);
      acc = MFMA(ul[kb], buh, acc);
      acc = MFMA(uh[kb], buh, acc);
    }
    float zk = zeta * zeta;
    float ak = -zk;
#pragma unroll
    for (int r = 0; r < 16; ++r) {
      t[r] = 2.0f * acc[r] - dg[r];
      Mac[r] += ak * t[r];
      tm2[r] = tm1[r];
      tm1[r] = t[r];
    }
    storeChi(B0, t, R, col, q);  // T2 -> B0 (P0 dead)
    __syncthreads();
    // k=3..DEG: T_k = 2 U T_{k-1} - T_{k-2}; even T in B0, odd in B1
    for (int k = 3; k <= DEG; ++k) {
      const short* src = (k & 1) ? B0 : B1;
      short* dst = (k & 1) ? B1 : B0;
#pragma unroll
      for (int r = 0; r < 16; ++r) acc[r] = 0.0f;
#pragma unroll
      for (int kb = 0; kb < 4; ++kb) {
        bf16x8 b = readFrag(src, kb, q, col);
        acc = MFMA(ul[kb], b, acc);
        acc = MFMA(uh[kb], b, acc);
      }
      zk *= -zeta;
      ak = -2.0f * zk / (float)k;
#pragma unroll
      for (int r = 0; r < 16; ++r) {
        t[r] = 2.0f * acc[r] - tm2[r];
        Mac[r] += ak * t[r];
        tm2[r] = tm1[r];
        tm1[r] = t[r];
      }
      if (k < DEG) storeChi(dst, t, R, col, q);
      __syncthreads();
    }
  }
  float* dst = ws + PM_OFF + (size_t)blockIdx.x * MSIZE;
#pragma unroll
  for (int r = 0; r < 16; ++r) dst[rowv[r] * 64 + col] = Mac[r];
}

// K4: E = expm(Mbar); G1 = Gs E Gs; Gis1 = sym(G1)^{-1/2}; C = Bs Gis1 -> ws.
__global__ __launch_bounds__(256) void k4_center(float* __restrict__ ws) {
  __shared__ __align__(16) float lA[MSIZE], lY[MSIZE], lZ[MSIZE], lW[MSIZE];
  __shared__ float red[257];
  const int tid = threadIdx.x;
  const int rt = tid >> 4, ct = tid & 15;
  loadMat(lA, ws + MBAR_OFF, tid);
  __syncthreads();
  if (tid == 0) {
    float mu = 0.f;
    for (int i = 0; i < NMAT; ++i) mu += lA[i * 65];
    red[256] = mu * (1.0f / NMAT);
  }
  __syncthreads();
  const float mu = red[256];
  float ss = 0.f;
#pragma unroll
  for (int j = 0; j < 4; ++j) {
    int base = j * 1024 + tid * 4;
    float4 v = *reinterpret_cast<const float4*>(lA + base);
    float4 idm = id4(base);
    v.x -= mu * idm.x;
    v.y -= mu * idm.y;
    v.z -= mu * idm.z;
    v.w -= mu * idm.w;
    ss += v.x * v.x + v.y * v.y + v.z * v.z + v.w * v.w;
    *reinterpret_cast<float4*>(lA + base) = v;
  }
  red[tid] = ss;
  __syncthreads();
  for (int off = 128; off > 0; off >>= 1) {
    if (tid < off) red[tid] += red[tid + off];
    __syncthreads();
  }
  float nrm = sqrtf(red[0]);
  int s = 0;
  while (nrm > 0.25f && s < 12) {
    nrm *= 0.5f;
    s++;
  }
  const float dscale = exp2f((float)-s);
#pragma unroll
  for (int j = 0; j < 4; ++j) {
    int base = j * 1024 + tid * 4;
    float4 v = *reinterpret_cast<const float4*>(lA + base);
    v.x *= dscale;
    v.y *= dscale;
    v.z *= dscale;
    v.w *= dscale;
    *reinterpret_cast<float4*>(lA + base) = v;
    float4 idm = id4(base);
    *reinterpret_cast<float4*>(lY + base) =
        make_float4(idm.x + v.x * 0.125f, idm.y + v.y * 0.125f,
                    idm.z + v.z * 0.125f, idm.w + v.w * 0.125f);
  }
  __syncthreads();
  float p[4][4];
  for (int j = 7; j >= 1; --j) {
    mm64T(lA, lY, rt, ct, p);
    __syncthreads();
    float w[4][4];
    const float rj = 1.0f / (float)j;
#pragma unroll
    for (int i = 0; i < 4; ++i)
#pragma unroll
      for (int jj = 0; jj < 4; ++jj)
        w[i][jj] =
            p[i][jj] * rj + (((rt * 4 + i) == (ct * 4 + jj)) ? 1.0f : 0.0f);
    storeTile(lY, rt, ct, w);
    __syncthreads();
  }
  for (int tq = 0; tq < s; ++tq) {
    mm64T(lY, lY, rt, ct, p);
    __syncthreads();
    storeTile(lY, rt, ct, p);
    __syncthreads();
  }
  const float emu = expf(mu);
#pragma unroll
  for (int j = 0; j < 4; ++j) {
    int base = j * 1024 + tid * 4;
    float4 v = *reinterpret_cast<const float4*>(lY + base);
    v.x *= emu;
    v.y *= emu;
    v.z *= emu;
    v.w *= emu;
    *reinterpret_cast<float4*>(lY + base) = v;
  }
  __syncthreads();
  loadMat(lZ, ws + GS_OFF, tid);
  __syncthreads();
  mm64T(lY, lZ, rt, ct, p);  // E Gs
  __syncthreads();
  storeTile(lW, rt, ct, p);
  __syncthreads();
  mm64T(lZ, lW, rt, ct, p);  // G1 = Gs E Gs
  __syncthreads();
  storeTile(lA, rt, ct, p);
  __syncthreads();
  float qq[4][4];
#pragma unroll
  for (int i = 0; i < 4; ++i)
#pragma unroll
    for (int j = 0; j < 4; ++j)
      qq[i][j] = 0.5f * (p[i][j] + lA[(ct * 4 + j) * NMAT + rt * 4 + i]);
  __syncthreads();
  storeTile(lA, rt, ct, qq);
  __syncthreads();
  float c = block_ns(lA, lY, lZ, lW, red, NS_ITERS_MEAN);
  const float rs = 1.0f / sqrtf(c);
#pragma unroll
  for (int j = 0; j < 4; ++j) {  // Gis1 -> lY
    int base = j * 1024 + tid * 4;
    float4 v = *reinterpret_cast<const float4*>(lZ + base);
    *reinterpret_cast<float4*>(lY + base) =
        make_float4(v.x * rs, v.y * rs, v.z * rs, v.w * rs);
  }
  __syncthreads();
  loadMat(lZ, ws + BS_OFF, tid);
  __syncthreads();
  mm64T(lZ, lY, rt, ct, p);  // C = Bs Gis1
#pragma unroll
  for (int i = 0; i < 4; ++i)
#pragma unroll
    for (int j = 0; j < 4; ++j)
      ws[C_OFF + (rt * 4 + i) * NMAT + ct * 4 + j] = p[i][j];
}

// ============================ K5: out = C X C^T (MFMA) ======================
__global__ __launch_bounds__(256, 3) void k5_out_mfma(
    const float* __restrict__ x, const float* __restrict__ ws,
    float* __restrict__ out) {
  __shared__ __align__(16) short Ch[GSTR * 8], Cl[GSTR * 8];
  __shared__ __align__(16) short Ah[GSTR * 8], Al[GSTR * 8];
  __shared__ __align__(16) short Bh[GSTR * 8], Bl[GSTR * 8];
  const int tid = threadIdx.x;
  const int w4 = tid >> 6;
  const int R = w4 >> 1, Cb = w4 & 1;
  const int lane = tid & 63;
  const int ln = lane & 31, q = lane >> 5;
  const int col = 32 * Cb + ln;
  const int arow = 32 * R + ln;

  int rowv[16];
#pragma unroll
  for (int r = 0; r < 16; ++r)
    rowv[r] = 32 * R + (r & 3) + 8 * (r >> 2) + 4 * q;

  stageT(ws + C_OFF, Ch, Cl, tid);  // arr = C^T (serves both roles)
  __syncthreads();

  for (int mat = blockIdx.x; mat < BATCH; mat += NBLK_MM) {
    stageT(x + (size_t)mat * MSIZE, Ah, Al, tid);  // X hi/lo (output accuracy)
    __syncthreads();
    floatx16 acc;
#pragma unroll
    for (int r = 0; r < 16; ++r) acc[r] = 0.0f;
#pragma unroll
    for (int kb = 0; kb < 4; ++kb) {
      bf16x8 axh = readFrag(Ah, kb, q, arow);
      bf16x8 axl = readFrag(Al, kb, q, arow);
      bf16x8 cbh = readFrag(Ch, kb, q, col);
      bf16x8 cbl = readFrag(Cl, kb, q, col);
      acc = MFMA(axl, cbh, acc);
      acc = MFMA(axh, cbl, acc);
      acc = MFMA(axh, cbh, acc);
    }
    float t[16];
#pragma unroll
    for (int r = 0; r < 16; ++r) t[r] = acc[r];
    storeChl(Bh, Bl, t, R, col, q);  // P' = X C^T, hi/lo
    __syncthreads();
#pragma unroll
    for (int r = 0; r < 16; ++r) acc[r] = 0.0f;
#pragma unroll
    for (int kb = 0; kb < 4; ++kb) {
      bf16x8 cah = readFrag(Ch, kb, q, arow);
      bf16x8 cal = readFrag(Cl, kb, q, arow);
      bf16x8 bph = readFrag(Bh, kb, q, col);
      bf16x8 bpl = readFrag(Bl, kb, q, col);
      acc = MFMA(cal, bph, acc);
      acc = MFMA(cah, bpl, acc);
      acc = MFMA(cah, bph, acc);
    }
    float* dst = out + (size_t)mat * MSIZE;
#pragma unroll
    for (int r = 0; r < 16; ++r) dst[rowv[r] * 64 + col] = acc[r];
    __syncthreads();
  }
}

extern "C" void kernel_launch(void* const* d_in, const int* in_sizes, int n_in,
                              void* d_out, int out_size, void* d_ws,
                              size_t ws_size, hipStream_t stream) {
  const float* x = (const float*)d_in[0];
  const float* bias = (const float*)d_in[1];
  float* out = (float*)d_out;
  float* ws = (float*)d_ws;
  const float invB = 1.0f / (float)BATCH;

  k1_mean_bias<<<NBLK_RED + 1, 256, 0, stream>>>(x, bias, ws);
  k_reduce_parts<<<4, 256, 0, stream>>>(ws + PG_OFF, ws + G_OFF, NBLK_RED,
                                        invB);
  k2_mean_ns<<<1, 256, 0, stream>>>(ws);
  k3_logsum_mfma<<<NBLK_MM, 256, 0, stream>>>(x, ws);
  k_reduce_parts<<<4, 256, 0, stream>>>(ws + PM_OFF, ws + MBAR_OFF, NBLK_MM,
                                        invB);
  k4_center<<<1, 256, 0, stream>>>(ws);
  k5_out_mfma<<<NBLK_MM, 256, 0, stream>>>(x, ws, out);
}